// Round 2
// baseline (623.425 us; speedup 1.0000x reference)
//
#include <hip/hip_runtime.h>
#include <hip/hip_bf16.h>

typedef __bf16 bf16;
typedef __attribute__((ext_vector_type(8))) __bf16 bf16x8;
typedef __attribute__((ext_vector_type(4))) __bf16 bf16x4;
typedef __attribute__((ext_vector_type(16))) float f32x16;

#define N_ROWS 16384
#define DIM 256
#define INV_T 14.2857142857f /* 1/0.07 */
#define JSPLIT 2             /* j-range split factor: grid = 256*JSPLIT blocks */

// ws layout: [0, 8MB) bf16 A; [8MB, +64KB) float T[16384]; then float D[16384]
#define WS_T_OFF (N_ROWS * DIM * 2)
#define WS_D_OFF (WS_T_OFF + N_ROWS * 4)

// Kernel 1: L2-normalize rows (fp32 math), emit bf16 matrix to workspace.
// Also: zero T[], zero d_out, and compute per-row diag correction
// D[row] = (1 - s2)/T where s2 = sum(bf16(a)^2) — reproduces the MFMA
// diagonal so the bf16 rounding of the diagonal logit cancels.
__global__ void __launch_bounds__(256) normalize_kernel(const float* __restrict__ in,
                                                        bf16* __restrict__ out,
                                                        float* __restrict__ Tg,
                                                        float* __restrict__ Dg,
                                                        float* __restrict__ loss_out) {
    if (blockIdx.x == 0 && threadIdx.x == 0) loss_out[0] = 0.0f;
    if (blockIdx.x < 64) Tg[blockIdx.x * 256 + threadIdx.x] = 0.0f;

    const int row  = blockIdx.x * 4 + (threadIdx.x >> 6);
    const int lane = threadIdx.x & 63;
    const float4* rp = (const float4*)(in + (size_t)row * DIM);
    float4 v = rp[lane];
    float ss = v.x * v.x + v.y * v.y + v.z * v.z + v.w * v.w;
#pragma unroll
    for (int m = 1; m < 64; m <<= 1) ss += __shfl_xor(ss, m, 64);
    float inv = 1.0f / fmaxf(sqrtf(ss), 1e-12f);
    bf16x4 o;
    o[0] = (bf16)(v.x * inv);
    o[1] = (bf16)(v.y * inv);
    o[2] = (bf16)(v.z * inv);
    o[3] = (bf16)(v.w * inv);
    *(bf16x4*)(out + (size_t)row * DIM + lane * 4) = o;

    // s2 = row self-dot in bf16 (what the MFMA diagonal will compute)
    float f0 = (float)o[0], f1 = (float)o[1], f2 = (float)o[2], f3 = (float)o[3];
    float s2 = f0 * f0 + f1 * f1 + f2 * f2 + f3 * f3;
#pragma unroll
    for (int m = 1; m < 64; m <<= 1) s2 += __shfl_xor(s2, m, 64);
    if (lane == 0) Dg[row] = (1.0f - s2) * INV_T;
}

// Kernel 2: fused A*A^T + fixed-shift (diag = provable row max) softmax
// denominator. Grid = 256 row-groups x JSPLIT j-parts. Block = 8 waves,
// 64 rows/block; each wave holds all 64 rows' A fragments in registers
// (128 VGPRs) and walks its j-part's 32-col tiles strided by 8.
// C/D layout (32x32x16): col = lane&31, row = (reg&3)+8*(reg>>2)+4*(lane>>5).
__global__ void __launch_bounds__(512, 4) loss_kernel(const bf16* __restrict__ A,
                                                      float* __restrict__ Tg) {
    __shared__ float Tsum[64];
    const int wave = threadIdx.x >> 6;
    const int lane = threadIdx.x & 63;
    const int lo = lane & 31, hi = lane >> 5;
    const int rb = (blockIdx.x / JSPLIT) * 64;
    const int jpart = blockIdx.x % JSPLIT;
    const int JT = (N_ROWS / 32) / JSPLIT;  // j-tiles per part

    if (threadIdx.x < 64) Tsum[threadIdx.x] = 0.0f;

    bf16x8 a0[16], a1[16];
    {
        const bf16* ap0 = A + (size_t)(rb + lo) * DIM + 8 * hi;
        const bf16* ap1 = ap0 + 32 * DIM;
#pragma unroll
        for (int kk = 0; kk < 16; ++kk) {
            a0[kk] = *(const bf16x8*)(ap0 + 16 * kk);
            a1[kk] = *(const bf16x8*)(ap1 + 16 * kk);
        }
    }

    float s0[16], s1[16];
#pragma unroll
    for (int r = 0; r < 16; ++r) { s0[r] = 0.0f; s1[r] = 0.0f; }

    const float K1 = 20.6099203f;  // 1/(0.07*ln2): exp((dot-1)/T)=exp2(dot*K1-K1)

    for (int jt = jpart * JT + wave; jt < (jpart + 1) * JT; jt += 8) {
        const bf16* bp = A + (size_t)(jt * 32 + lo) * DIM + 8 * hi;
        f32x16 c0, c1;
#pragma unroll
        for (int r = 0; r < 16; ++r) { c0[r] = 0.0f; c1[r] = 0.0f; }
#pragma unroll
        for (int kk = 0; kk < 16; ++kk) {
            bf16x8 b = *(const bf16x8*)(bp + 16 * kk);
            c0 = __builtin_amdgcn_mfma_f32_32x32x16_bf16(a0[kk], b, c0, 0, 0, 0);
            c1 = __builtin_amdgcn_mfma_f32_32x32x16_bf16(a1[kk], b, c1, 0, 0, 0);
        }
#pragma unroll
        for (int r = 0; r < 16; ++r) {
            s0[r] += __builtin_amdgcn_exp2f(fmaf(c0[r], K1, -K1));
            s1[r] += __builtin_amdgcn_exp2f(fmaf(c1[r], K1, -K1));
        }
    }

    // Reduce over the 32 column-lanes (cols = lane&31).
#pragma unroll
    for (int r = 0; r < 16; ++r) {
        float x0 = s0[r], x1 = s1[r];
#pragma unroll
        for (int m = 1; m < 32; m <<= 1) {
            x0 += __shfl_xor(x0, m, 64);
            x1 += __shfl_xor(x1, m, 64);
        }
        s0[r] = x0; s1[r] = x1;
    }

    __syncthreads();
    if (lo == 0) {
#pragma unroll
        for (int r = 0; r < 16; ++r) {
            const int ro = (r & 3) + 8 * (r >> 2) + 4 * hi;
            atomicAdd(&Tsum[ro], s0[r]);
            atomicAdd(&Tsum[32 + ro], s1[r]);
        }
    }
    __syncthreads();

    if (threadIdx.x < 64) atomicAdd(&Tg[rb + threadIdx.x], Tsum[threadIdx.x]);
}

// Kernel 3: loss_i = log(T_i) + D_i, mean over rows.
__global__ void __launch_bounds__(256) final_kernel(const float* __restrict__ Tg,
                                                    const float* __restrict__ Dg,
                                                    float* __restrict__ out) {
    __shared__ float red[4];
    const int i = blockIdx.x * 256 + threadIdx.x;
    float c = (logf(Tg[i]) + Dg[i]) * (1.0f / (float)N_ROWS);
#pragma unroll
    for (int m = 1; m < 64; m <<= 1) c += __shfl_xor(c, m, 64);
    if ((threadIdx.x & 63) == 0) red[threadIdx.x >> 6] = c;
    __syncthreads();
    if (threadIdx.x == 0)
        atomicAdd(out, red[0] + red[1] + red[2] + red[3]);
}

extern "C" void kernel_launch(void* const* d_in, const int* in_sizes, int n_in,
                              void* d_out, int out_size, void* d_ws, size_t ws_size,
                              hipStream_t stream) {
    const float* emb = (const float*)d_in[0];
    float* out = (float*)d_out;
    bf16* Abf = (bf16*)d_ws;
    float* Tg = (float*)((char*)d_ws + WS_T_OFF);
    float* Dg = (float*)((char*)d_ws + WS_D_OFF);

    hipLaunchKernelGGL(normalize_kernel, dim3(N_ROWS / 4), dim3(256), 0, stream,
                       emb, Abf, Tg, Dg, out);
    hipLaunchKernelGGL(loss_kernel, dim3(256 * JSPLIT), dim3(512), 0, stream,
                       Abf, Tg);
    hipLaunchKernelGGL(final_kernel, dim3(N_ROWS / 256), dim3(256), 0, stream,
                       Tg, Dg, out);
}

// Round 3
// 212.497 us; speedup vs baseline: 2.9338x; 2.9338x over previous
//
#include <hip/hip_runtime.h>
#include <hip/hip_bf16.h>

typedef __bf16 bf16;
typedef __attribute__((ext_vector_type(8))) __bf16 bf16x8;
typedef __attribute__((ext_vector_type(4))) __bf16 bf16x4;
typedef __attribute__((ext_vector_type(16))) float f32x16;

#define N_ROWS 16384
#define DIM 256
#define NT 128               /* 128 row/col tiles of 128 */
#define INV_T 14.2857142857f /* 1/0.07 */
#define K1C 20.6099203f      /* 1/(0.07*ln2) */

#define WS_T_OFF (N_ROWS * DIM * 2)
#define WS_D_OFF (WS_T_OFF + N_ROWS * 4)

#define GLOAD_LDS(g, l)                                        \
    __builtin_amdgcn_global_load_lds(                          \
        (const __attribute__((address_space(1))) void*)(g),    \
        (__attribute__((address_space(3))) void*)(l), 16, 0, 0)

// Kernel 1: L2-normalize rows (fp32 math) -> bf16 matrix in ws. Also zeros
// T[], zeros d_out, and computes D[row] = (1 - s2)/T with s2 = sum(bf16(a)^2)
// (reproduces the MFMA diagonal so its bf16 rounding error cancels in the log).
__global__ void __launch_bounds__(256) normalize_kernel(const float* __restrict__ in,
                                                        bf16* __restrict__ out,
                                                        float* __restrict__ Tg,
                                                        float* __restrict__ Dg,
                                                        float* __restrict__ loss_out) {
    if (blockIdx.x == 0 && threadIdx.x == 0) loss_out[0] = 0.0f;
    if (blockIdx.x < 64) Tg[blockIdx.x * 256 + threadIdx.x] = 0.0f;

    const int row  = blockIdx.x * 4 + (threadIdx.x >> 6);
    const int lane = threadIdx.x & 63;
    const float4* rp = (const float4*)(in + (size_t)row * DIM);
    float4 v = rp[lane];
    float ss = v.x * v.x + v.y * v.y + v.z * v.z + v.w * v.w;
#pragma unroll
    for (int m = 1; m < 64; m <<= 1) ss += __shfl_xor(ss, m, 64);
    float inv = 1.0f / fmaxf(sqrtf(ss), 1e-12f);
    bf16x4 o;
    o[0] = (bf16)(v.x * inv);
    o[1] = (bf16)(v.y * inv);
    o[2] = (bf16)(v.z * inv);
    o[3] = (bf16)(v.w * inv);
    *(bf16x4*)(out + (size_t)row * DIM + lane * 4) = o;

    float f0 = (float)o[0], f1 = (float)o[1], f2 = (float)o[2], f3 = (float)o[3];
    float s2 = f0 * f0 + f1 * f1 + f2 * f2 + f3 * f3;
#pragma unroll
    for (int m = 1; m < 64; m <<= 1) s2 += __shfl_xor(s2, m, 64);
    if (lane == 0) Dg[row] = (1.0f - s2) * INV_T;
}

// Kernel 2: symmetric fused A*A^T + fixed-shift softmax denominator.
// Upper-triangular 128x128 tiles (jt >= it). 256 threads = 4 waves; wave w
// computes quadrant rows (w>>1)*64, cols (w&1)*64 as 2x2 MFMA 32x32x16 tiles.
// K=256 staged in 4 slabs of 64 via global_load_lds (16B), with an XOR
// chunk-swizzle applied on the GLOBAL source address (LDS dest must stay
// uniform-base + lane*16) so fragment reads spread across banks.
// Off-diag tiles: row sums -> Tg[it rows], col sums -> Tg[jt rows].
__global__ void __launch_bounds__(256, 3)
loss_kernel(const bf16* __restrict__ A, float* __restrict__ Tg) {
    __shared__ bf16 As[128 * 64];
    __shared__ bf16 Bs[128 * 64];
    __shared__ float Rs[128];
    __shared__ float Cs[128];

    const int tid = threadIdx.x;
    const int w  = tid >> 6;
    const int l  = tid & 63;
    const int lo = l & 31, hi = l >> 5;

    // decode (it, jt) with jt >= it from linear upper-tri index
    const int b = blockIdx.x;
    int it = (int)(((float)(2 * NT + 1) -
                    sqrtf((float)((2 * NT + 1) * (2 * NT + 1)) - 8.0f * (float)b)) * 0.5f);
    while (it > 0 && it * NT - (it * (it - 1)) / 2 > b) --it;
    while ((it + 1) * NT - ((it + 1) * it) / 2 <= b) ++it;
    const int jt = it + (b - (it * NT - (it * (it - 1)) / 2));

    if (tid < 128) { Rs[tid] = 0.0f; Cs[tid] = 0.0f; }

    // staging: thread covers (row srow within 32-row group, swizzled chunk)
    const int srow   = w * 8 + (l >> 3);
    const int schunk = (l & 7) ^ ((l >> 3) & 7);
    const bf16* gA = A + ((size_t)(it * 128) + srow) * DIM + schunk * 8;
    const bf16* gB = A + ((size_t)(jt * 128) + srow) * DIM + schunk * 8;

    f32x16 c00, c01, c10, c11;
#pragma unroll
    for (int r = 0; r < 16; ++r) { c00[r] = 0.f; c01[r] = 0.f; c10[r] = 0.f; c11[r] = 0.f; }

    const int arow = (w >> 1) * 64;
    const int brow = (w & 1) * 64;
    const int rsw  = lo & 7;  // row component of the chunk swizzle

    for (int ks = 0; ks < 4; ++ks) {
        if (ks) __syncthreads();  // previous slab's compute done
#pragma unroll
        for (int m = 0; m < 4; ++m) {
            GLOAD_LDS(gA + (size_t)(m * 32) * DIM + ks * 64, &As[m * 2048 + w * 512]);
            GLOAD_LDS(gB + (size_t)(m * 32) * DIM + ks * 64, &Bs[m * 2048 + w * 512]);
        }
        __syncthreads();  // slab staged
#pragma unroll 2
        for (int k16 = 0; k16 < 4; ++k16) {
            const int co = ((k16 * 2 + hi) ^ rsw) * 8;
            bf16x8 a0 = *(const bf16x8*)&As[(arow + lo) * 64 + co];
            bf16x8 a1 = *(const bf16x8*)&As[(arow + 32 + lo) * 64 + co];
            bf16x8 b0 = *(const bf16x8*)&Bs[(brow + lo) * 64 + co];
            bf16x8 b1 = *(const bf16x8*)&Bs[(brow + 32 + lo) * 64 + co];
            c00 = __builtin_amdgcn_mfma_f32_32x32x16_bf16(a0, b0, c00, 0, 0, 0);
            c01 = __builtin_amdgcn_mfma_f32_32x32x16_bf16(a0, b1, c01, 0, 0, 0);
            c10 = __builtin_amdgcn_mfma_f32_32x32x16_bf16(a1, b0, c10, 0, 0, 0);
            c11 = __builtin_amdgcn_mfma_f32_32x32x16_bf16(a1, b1, c11, 0, 0, 0);
        }
    }

    // exp transform: exp((dot-1)/T) = exp2(dot*K1 - K1); diag is provable max
#pragma unroll
    for (int r = 0; r < 16; ++r) {
        c00[r] = __builtin_amdgcn_exp2f(fmaf(c00[r], K1C, -K1C));
        c01[r] = __builtin_amdgcn_exp2f(fmaf(c01[r], K1C, -K1C));
        c10[r] = __builtin_amdgcn_exp2f(fmaf(c10[r], K1C, -K1C));
        c11[r] = __builtin_amdgcn_exp2f(fmaf(c11[r], K1C, -K1C));
    }

    // row sums over this tile's 128 cols -> Rs[tile row]
    // C/D layout: col = lane&31, row = (r&3) + 8*(r>>2) + 4*hi
#pragma unroll
    for (int s = 0; s < 2; ++s) {
#pragma unroll
        for (int r = 0; r < 16; ++r) {
            float v = s ? (c10[r] + c11[r]) : (c00[r] + c01[r]);
            v += __shfl_xor(v, 1);
            v += __shfl_xor(v, 2);
            v += __shfl_xor(v, 4);
            v += __shfl_xor(v, 8);
            v += __shfl_xor(v, 16);
            if (lo == 0)
                atomicAdd(&Rs[arow + s * 32 + (r & 3) + 8 * (r >> 2) + 4 * hi], v);
        }
    }
    // col sums over this tile's 128 rows -> Cs[tile col]
    {
        float v0 = 0.f, v1 = 0.f;
#pragma unroll
        for (int r = 0; r < 16; ++r) {
            v0 += c00[r] + c10[r];
            v1 += c01[r] + c11[r];
        }
        v0 += __shfl_xor(v0, 32);
        v1 += __shfl_xor(v1, 32);
        if (hi == 0) {
            atomicAdd(&Cs[brow + lo], v0);
            atomicAdd(&Cs[brow + 32 + lo], v1);
        }
    }
    __syncthreads();
    if (tid < 128) {
        atomicAdd(&Tg[it * 128 + tid], Rs[tid]);
        if (jt != it) atomicAdd(&Tg[jt * 128 + tid], Cs[tid]);
    }
}

// Kernel 3: loss_i = log(T_i) + D_i, mean over rows.
__global__ void __launch_bounds__(256) final_kernel(const float* __restrict__ Tg,
                                                    const float* __restrict__ Dg,
                                                    float* __restrict__ out) {
    __shared__ float red[4];
    const int i = blockIdx.x * 256 + threadIdx.x;
    float c = (logf(Tg[i]) + Dg[i]) * (1.0f / (float)N_ROWS);
#pragma unroll
    for (int m = 1; m < 64; m <<= 1) c += __shfl_xor(c, m, 64);
    if ((threadIdx.x & 63) == 0) red[threadIdx.x >> 6] = c;
    __syncthreads();
    if (threadIdx.x == 0)
        atomicAdd(out, red[0] + red[1] + red[2] + red[3]);
}

extern "C" void kernel_launch(void* const* d_in, const int* in_sizes, int n_in,
                              void* d_out, int out_size, void* d_ws, size_t ws_size,
                              hipStream_t stream) {
    const float* emb = (const float*)d_in[0];
    float* out = (float*)d_out;
    bf16* Abf = (bf16*)d_ws;
    float* Tg = (float*)((char*)d_ws + WS_T_OFF);
    float* Dg = (float*)((char*)d_ws + WS_D_OFF);

    hipLaunchKernelGGL(normalize_kernel, dim3(N_ROWS / 4), dim3(256), 0, stream,
                       emb, Abf, Tg, Dg, out);
    hipLaunchKernelGGL(loss_kernel, dim3(NT * (NT + 1) / 2), dim3(256), 0, stream,
                       Abf, Tg);
    hipLaunchKernelGGL(final_kernel, dim3(N_ROWS / 256), dim3(256), 0, stream,
                       Tg, Dg, out);
}